// Round 1
// baseline (235.569 us; speedup 1.0000x reference)
//
#include <hip/hip_runtime.h>

#define MTOT 16384        // 8*2048 tokens
#define NFEAT 512         // out features
#define KTOT 4608         // 512 inputs * 9 segments
#define NGRP 576          // KTOT / 8

typedef float f32x4 __attribute__((ext_vector_type(4)));
typedef short s16x8 __attribute__((ext_vector_type(8)));
typedef unsigned long long u64x2 __attribute__((ext_vector_type(2)));

__device__ __forceinline__ int div9(int c) { return (c * 7282) >> 16; }  // exact for 0 <= c < 32768

// ---------------- P1: x -> code_t[g][m] (u8) ----------------
// code byte: low nibble = 1+pos of j0's one-hot within the 8-col group (0 = none),
//            high nibble = same for j1 (second j-group overlapping this 8-col group).
__global__ __launch_bounds__(256) void build_codes(const float* __restrict__ x,
                                                   unsigned char* __restrict__ codeT) {
  __shared__ unsigned char segt[64][68];
  const int tid = threadIdx.x;
  const int mt = blockIdx.x;   // 0..255 (64 tokens each)
  const int jt = blockIdx.y;   // 0..7   (64 inputs each -> exactly 72 groups of 8 cols)
  const int m0 = mt * 64;
  const float4* x4 = (const float4*)x;
  // exact float32 knots t[k] = float32(k/9.0)  (matches np.linspace(0,1,10,f32))
  const float T1 = (float)(1.0/9.0), T2 = (float)(2.0/9.0), T3 = (float)(3.0/9.0),
              T4 = (float)(4.0/9.0), T5 = (float)(5.0/9.0), T6 = (float)(6.0/9.0),
              T7 = (float)(7.0/9.0), T8 = (float)(8.0/9.0);
#pragma unroll
  for (int it = 0; it < 4; ++it) {
    int f = it * 256 + tid;
    int m = f >> 4, jq = f & 15;
    float4 v = x4[(size_t)(m0 + m) * 128 + jt * 16 + jq];
    uchar4 sv;
    {
      float xv = v.x;
      sv.x = (unsigned char)((xv>=T1)+(xv>=T2)+(xv>=T3)+(xv>=T4)+(xv>=T5)+(xv>=T6)+(xv>=T7)+(xv>=T8));
    }
    {
      float xv = v.y;
      sv.y = (unsigned char)((xv>=T1)+(xv>=T2)+(xv>=T3)+(xv>=T4)+(xv>=T5)+(xv>=T6)+(xv>=T7)+(xv>=T8));
    }
    {
      float xv = v.z;
      sv.z = (unsigned char)((xv>=T1)+(xv>=T2)+(xv>=T3)+(xv>=T4)+(xv>=T5)+(xv>=T6)+(xv>=T7)+(xv>=T8));
    }
    {
      float xv = v.w;
      sv.w = (unsigned char)((xv>=T1)+(xv>=T2)+(xv>=T3)+(xv>=T4)+(xv>=T5)+(xv>=T6)+(xv>=T7)+(xv>=T8));
    }
    *(uchar4*)&segt[m][jq * 4] = sv;
  }
  __syncthreads();
#pragma unroll
  for (int p = 0; p < 18; ++p) {
    int u = p * 256 + tid;
    int gl = u >> 6, m = u & 63;          // one g per 64-lane wave -> coalesced store
    int c0 = jt * 576 + gl * 8;           // global col of group start
    int j0 = div9(c0), j1 = div9(c0 + 7);
    int s0 = segt[m][j0 - jt * 64];
    int pos0 = j0 * 9 + s0 - c0;
    unsigned code = (pos0 >= 0 && pos0 < 8) ? (unsigned)(pos0 + 1) : 0u;
    if (j1 != j0) {
      int s1 = segt[m][j1 - jt * 64];
      int pos1 = j1 * 9 + s1 - c0;        // always >= 1 when j1 != j0
      if (pos1 < 8) code |= (unsigned)(pos1 + 1) << 4;
    }
    codeT[(size_t)(jt * 72 + gl) * MTOT + m0 + m] = (unsigned char)code;
  }
}

// ---------------- P2: coeffs -> Bmat[i][k] (bf16), k = j*9+s ----------------
__global__ __launch_bounds__(256) void build_b(const float* __restrict__ coeffs,
                                               unsigned short* __restrict__ Bmat) {
  __shared__ float crow[6144];
  const int tid = threadIdx.x;
  const int i = blockIdx.x;  // out feature
  const float4* c4 = (const float4*)(coeffs + (size_t)i * 6144);
  float4* l4 = (float4*)crow;
#pragma unroll
  for (int p = 0; p < 6; ++p) l4[p * 256 + tid] = c4[p * 256 + tid];
  __syncthreads();
#pragma unroll
  for (int p = 0; p < 18; ++p) {
    int k = p * 256 + tid;
    int j = div9(k), s = k - j * 9;
    float v = crow[j * 12 + s] + crow[j * 12 + s + 1] + crow[j * 12 + s + 2];
    unsigned u = __float_as_uint(v);
    unsigned rn = (u + 0x7FFFu + ((u >> 16) & 1u)) >> 16;  // RNE f32->bf16
    Bmat[(size_t)i * KTOT + k] = (unsigned short)rn;
  }
}

// ---------------- main: one-hot bf16 MFMA GEMM  C[16384,512] = A @ B ----------------
// LDS tiles stored fragment-major: slot pp = sub16*2 + kstep, [pp][lane][8 bf16].
__global__ __launch_bounds__(256, 3) void kan_gemm(const unsigned char* __restrict__ codeT,
                                                   const unsigned short* __restrict__ Bmat,
                                                   float* __restrict__ out) {
  __shared__ __align__(16) short Alds[16 * 512];
  __shared__ __align__(16) short Blds[16 * 512];
  const int tid = threadIdx.x;
  const int lane = tid & 63;
  const int wid = tid >> 6;
  const int lm = lane & 15;  // row/col within 16
  const int lq = lane >> 4;  // quad -> k-subrange / C-row group
  // block swizzle: same nt lands on 2 XCDs (assuming round-robin x%8) -> B slice L2-resident
  const int bx = blockIdx.x;
  const int rr8 = bx & 7, qq = bx >> 3;
  const int nt = rr8 & 3;
  const int mt = qq * 2 + (rr8 >> 2);
  const int m0 = mt * 128, n0 = nt * 128;
  const int wr = wid >> 1, wc = wid & 1;  // 2x2 wave grid, each wave 64x64

  f32x4 acc[4][4] = {};

  for (int kt = 0; kt < 72; ++kt) {
    const int k0 = kt * 64;
    __syncthreads();  // protect LDS vs previous iter's reads
    // B staging via async global->LDS, fragment-major
#pragma unroll
    for (int p = 0; p < 4; ++p) {
      int pp = wid * 4 + p;
      int nsub = pp >> 1, ks = pp & 1;
      int i = n0 + nsub * 16 + lm;
      int kc = k0 + ks * 32 + lq * 8;
      const unsigned short* gp = Bmat + (size_t)i * KTOT + kc;
      __builtin_amdgcn_global_load_lds((const __attribute__((address_space(1))) void*)gp,
                                       (__attribute__((address_space(3))) void*)(Blds + pp * 512),
                                       16, 0, 0);
    }
    // A fragments computed in registers from one code byte each
#pragma unroll
    for (int p = 0; p < 4; ++p) {
      int pp = wid * 4 + p;
      int msub = pp >> 1, ks = pp & 1;
      int m = msub * 16 + lm;
      int c = k0 + ks * 32 + lq * 8;  // 8 cols = one code group (c % 8 == 0)
      unsigned code = codeT[(size_t)(c >> 3) * MTOT + m0 + m];
      unsigned long long lo = 0ull, hi = 0ull;
      unsigned nb0 = code & 15u, nb1 = code >> 4;
      if (nb0) {
        unsigned pos = nb0 - 1u;
        unsigned long long b = 0x3F80ull << ((pos & 3u) * 16u);
        if (pos < 4u) lo |= b; else hi |= b;
      }
      if (nb1) {
        unsigned pos = nb1 - 1u;
        unsigned long long b = 0x3F80ull << ((pos & 3u) * 16u);
        if (pos < 4u) lo |= b; else hi |= b;
      }
      u64x2 v; v.x = lo; v.y = hi;
      *(u64x2*)(Alds + pp * 512 + lane * 8) = v;  // ds_write_b128, lane-stride-1
    }
    __syncthreads();  // drains vmcnt (global_load_lds) + lgkm (ds_write)
#pragma unroll
    for (int ks = 0; ks < 2; ++ks) {
      s16x8 af[4], bf[4];
#pragma unroll
      for (int i = 0; i < 4; ++i)
        af[i] = *(const s16x8*)(Alds + ((wr * 4 + i) * 2 + ks) * 512 + lane * 8);
#pragma unroll
      for (int j = 0; j < 4; ++j)
        bf[j] = *(const s16x8*)(Blds + ((wc * 4 + j) * 2 + ks) * 512 + lane * 8);
#pragma unroll
      for (int i = 0; i < 4; ++i)
#pragma unroll
        for (int j = 0; j < 4; ++j)
          acc[i][j] = __builtin_amdgcn_mfma_f32_16x16x32_bf16(af[i], bf[j], acc[i][j], 0, 0, 0);
    }
  }
  // epilogue: C/D layout col=lane&15, row=quad*4+reg
#pragma unroll
  for (int i = 0; i < 4; ++i) {
#pragma unroll
    for (int j = 0; j < 4; ++j) {
      int tok = m0 + wr * 64 + i * 16 + lq * 4;
      int col = n0 + wc * 64 + j * 16 + lm;
      float* op = out + (size_t)tok * NFEAT + col;
#pragma unroll
      for (int rg = 0; rg < 4; ++rg) op[(size_t)rg * NFEAT] = acc[i][j][rg];
    }
  }
}

extern "C" void kernel_launch(void* const* d_in, const int* in_sizes, int n_in,
                              void* d_out, int out_size, void* d_ws, size_t ws_size,
                              hipStream_t stream) {
  const float* x = (const float*)d_in[0];        // [16384, 512] f32
  const float* coeffs = (const float*)d_in[1];   // [512, 512, 12] f32
  float* out = (float*)d_out;                    // [16384, 512] f32
  unsigned char* codeT = (unsigned char*)d_ws;                               // 576*16384 = 9.44 MB
  unsigned short* Bmat = (unsigned short*)((char*)d_ws + (size_t)NGRP * MTOT);  // 512*4608*2 = 4.72 MB

  build_codes<<<dim3(256, 8), dim3(256), 0, stream>>>(x, codeT);
  build_b<<<dim3(512), dim3(256), 0, stream>>>(coeffs, Bmat);
  kan_gemm<<<dim3(512), dim3(256), 0, stream>>>(codeT, Bmat, out);
}

// Round 2
// 222.275 us; speedup vs baseline: 1.0598x; 1.0598x over previous
//
#include <hip/hip_runtime.h>

#define MTOT 16384        // 8*2048 tokens
#define NFEAT 512         // out features
#define KTOT 4608         // 512 inputs * 9 segments

typedef float f32x4 __attribute__((ext_vector_type(4)));
typedef short s16x8 __attribute__((ext_vector_type(8)));

__device__ __forceinline__ int div9(int c) { return (c * 7282) >> 16; }  // exact for 0 <= c < 32768

#define GLDS(GP, LP) __builtin_amdgcn_global_load_lds( \
    (const __attribute__((address_space(1))) void*)(GP), \
    (__attribute__((address_space(3))) void*)(LP), 16, 0, 0)

// decode one code byte -> 8 bf16 one-hot fragment (16-bit slot pos gets 0x3F80)
__device__ __forceinline__ s16x8 decode_frag(unsigned code) {
  unsigned nb0 = code & 15u, nb1 = code >> 4;
  unsigned long long lo = 0ull, hi = 0ull;
  if (nb0) {
    unsigned p = nb0 - 1u;
    unsigned long long b = 0x3F80ull << ((p & 3u) * 16u);
    if (p < 4u) lo |= b; else hi |= b;
  }
  if (nb1) {
    unsigned p = nb1 - 1u;
    unsigned long long b = 0x3F80ull << ((p & 3u) * 16u);
    if (p < 4u) lo |= b; else hi |= b;
  }
  union { unsigned long long q[2]; s16x8 v; } u;
  u.q[0] = lo; u.q[1] = hi;
  return u.v;
}

// ---------------- P1: x -> code_t[g][m] (u8), 256-token tiles, uchar4 stores ----------------
__global__ __launch_bounds__(256) void build_codes(const float* __restrict__ x,
                                                   unsigned char* __restrict__ codeT) {
  __shared__ unsigned char segt[256][68];  // 17 KB, +pad
  const int tid = threadIdx.x;
  const int lane = tid & 63;
  const int wid = tid >> 6;
  const int mt = blockIdx.x;   // 0..63  (256 tokens each)
  const int jt = blockIdx.y;   // 0..7   (64 inputs each -> exactly 72 groups of 8 cols)
  const int m0 = mt * 256;
  const float4* x4 = (const float4*)x;
  const float T1 = (float)(1.0/9.0), T2 = (float)(2.0/9.0), T3 = (float)(3.0/9.0),
              T4 = (float)(4.0/9.0), T5 = (float)(5.0/9.0), T6 = (float)(6.0/9.0),
              T7 = (float)(7.0/9.0), T8 = (float)(8.0/9.0);
#pragma unroll
  for (int it = 0; it < 16; ++it) {
    int f = it * 256 + tid;
    int m = f >> 4, jq = f & 15;
    float4 v = x4[(size_t)(m0 + m) * 128 + jt * 16 + jq];
    uchar4 sv;
    { float xv = v.x; sv.x = (unsigned char)((xv>=T1)+(xv>=T2)+(xv>=T3)+(xv>=T4)+(xv>=T5)+(xv>=T6)+(xv>=T7)+(xv>=T8)); }
    { float xv = v.y; sv.y = (unsigned char)((xv>=T1)+(xv>=T2)+(xv>=T3)+(xv>=T4)+(xv>=T5)+(xv>=T6)+(xv>=T7)+(xv>=T8)); }
    { float xv = v.z; sv.z = (unsigned char)((xv>=T1)+(xv>=T2)+(xv>=T3)+(xv>=T4)+(xv>=T5)+(xv>=T6)+(xv>=T7)+(xv>=T8)); }
    { float xv = v.w; sv.w = (unsigned char)((xv>=T1)+(xv>=T2)+(xv>=T3)+(xv>=T4)+(xv>=T5)+(xv>=T6)+(xv>=T7)+(xv>=T8)); }
    *(uchar4*)&segt[m][jq * 4] = sv;
  }
  __syncthreads();
#pragma unroll
  for (int p = 0; p < 18; ++p) {
    int gl = p * 4 + wid;                 // 0..71
    int c0 = jt * 576 + gl * 8;
    int j0 = div9(c0), j1 = div9(c0 + 7);
    int j0l = j0 - jt * 64, j1l = j1 - jt * 64;
    uchar4 ob;
    unsigned char* pb = (unsigned char*)&ob;
#pragma unroll
    for (int c = 0; c < 4; ++c) {
      int m = (lane << 2) + c;
      int s0 = segt[m][j0l];
      int pos0 = j0 * 9 + s0 - c0;
      unsigned code = (pos0 >= 0 && pos0 < 8) ? (unsigned)(pos0 + 1) : 0u;
      if (j1 != j0) {
        int s1 = segt[m][j1l];
        int pos1 = j1 * 9 + s1 - c0;
        if (pos1 < 8) code |= (unsigned)(pos1 + 1) << 4;
      }
      pb[c] = (unsigned char)code;
    }
    *(uchar4*)(codeT + (size_t)(jt * 72 + gl) * MTOT + m0 + (lane << 2)) = ob;
  }
}

// ---------------- P2: coeffs -> Bmat[i][k] (bf16), 2048 blocks, direct loads ----------------
__global__ __launch_bounds__(256) void build_b(const float* __restrict__ coeffs,
                                               unsigned short* __restrict__ Bmat) {
  const int bx = blockIdx.x;
  const int i = bx >> 2, q = bx & 3;
  const int tid = threadIdx.x;
  const float* cb = coeffs + (size_t)i * 6144;
#pragma unroll
  for (int p = 0; p < 5; ++p) {
    int kl = p * 256 + tid;
    if (kl < 1152) {
      int k = q * 1152 + kl;
      int j = div9(k), s = k - j * 9;
      float v = cb[j * 12 + s] + cb[j * 12 + s + 1] + cb[j * 12 + s + 2];
      unsigned u = __float_as_uint(v);
      unsigned rn = (u + 0x7FFFu + ((u >> 16) & 1u)) >> 16;  // RNE f32->bf16
      Bmat[(size_t)i * KTOT + k] = (unsigned short)rn;
    }
  }
}

// ---------------- main: one-hot bf16 MFMA GEMM, single-barrier dbuf pipeline ----------------
__global__ __launch_bounds__(256, 2) void kan_gemm(const unsigned char* __restrict__ codeT,
                                                   const unsigned short* __restrict__ Bmat,
                                                   float* __restrict__ out) {
  __shared__ __align__(16) short Blds[2][16 * 512];  // 2 x 16KB, fragment-major
  const int tid = threadIdx.x;
  const int lane = tid & 63;
  const int wid = tid >> 6;
  const int lm = lane & 15;
  const int lq = lane >> 4;
  const int bx = blockIdx.x;
  const int rr8 = bx & 7, qq = bx >> 3;
  const int nt = rr8 & 3;
  const int mt = qq * 2 + (rr8 >> 2);
  const int m0 = mt * 128, n0 = nt * 128;
  const int wr = wid >> 1, wc = wid & 1;

  // B staging pointers (loop-carried, += 64 shorts per kt). slots pp=wid*4+p, p=ns*2+ks.
  const unsigned short* gB0 = Bmat + (size_t)(n0 + (wid * 2 + 0) * 16 + lm) * KTOT + lq * 8;
  const unsigned short* gB1 = Bmat + (size_t)(n0 + (wid * 2 + 1) * 16 + lm) * KTOT + lq * 8;
  // code pointers (loop-carried, += 8*MTOT per kt), frag f=i*2+ks, imm offset i*16
  const unsigned char* gC0 = codeT + (size_t)(lq) * MTOT + m0 + wr * 64 + lm;
  const unsigned char* gC1 = codeT + (size_t)(4 + lq) * MTOT + m0 + wr * 64 + lm;

  f32x4 acc[4][4] = {};
  s16x8 afA[8], afB[8];
  unsigned char cr[8];

#define LOAD_CR() do { \
    cr[0]=gC0[0]; cr[2]=gC0[16]; cr[4]=gC0[32]; cr[6]=gC0[48]; \
    cr[1]=gC1[0]; cr[3]=gC1[16]; cr[5]=gC1[32]; cr[7]=gC1[48]; \
    gC0 += (size_t)8 * MTOT; gC1 += (size_t)8 * MTOT; } while(0)

#define ISSUE_B(buf) do { \
    short* base = &Blds[buf][0] + wid * 2048; \
    GLDS(gB0,      base);        \
    GLDS(gB0 + 32, base + 512);  \
    GLDS(gB1,      base + 1024); \
    GLDS(gB1 + 32, base + 1536); \
    gB0 += 64; gB1 += 64; } while(0)

#define COMPUTE(AF, buf) do { \
    _Pragma("unroll") \
    for (int ks = 0; ks < 2; ++ks) { \
      s16x8 bf[4]; \
      _Pragma("unroll") \
      for (int j = 0; j < 4; ++j) \
        bf[j] = *(const s16x8*)&Blds[buf][(((wc * 4 + j) * 2 + ks) * 512) + lane * 8]; \
      _Pragma("unroll") \
      for (int i2 = 0; i2 < 4; ++i2) \
        _Pragma("unroll") \
        for (int j = 0; j < 4; ++j) \
          acc[i2][j] = __builtin_amdgcn_mfma_f32_16x16x32_bf16(AF[i2 * 2 + ks], bf[j], acc[i2][j], 0, 0, 0); \
    } } while(0)

  // prologue: stage kt=0
  LOAD_CR();
  ISSUE_B(0);
#pragma unroll
  for (int f = 0; f < 8; ++f) afA[f] = decode_frag(cr[f]);

#pragma unroll 1
  for (int kt = 0; kt < 72; kt += 2) {
    // even phase: compute kt from afA + Blds[0]; prefetch kt+1
    __syncthreads();                 // Blds[0] staged (drains old loads only)
    LOAD_CR();                       // codes for kt+1 -> regs (async)
    ISSUE_B(1);                      // B tile kt+1 -> Blds[1] (async)
    COMPUTE(afA, 0);                 // 32 MFMA ~ 1242 cyc of latency cover
#pragma unroll
    for (int f = 0; f < 8; ++f) afB[f] = decode_frag(cr[f]);

    // odd phase: compute kt+1 from afB + Blds[1]; prefetch kt+2
    __syncthreads();
    if (kt < 70) {
      LOAD_CR();
      ISSUE_B(0);
    }
    COMPUTE(afB, 1);
    if (kt < 70) {
#pragma unroll
      for (int f = 0; f < 8; ++f) afA[f] = decode_frag(cr[f]);
    }
  }

  // epilogue: C/D layout col=lane&15, row=quad*4+reg (verified in R1)
#pragma unroll
  for (int i = 0; i < 4; ++i) {
#pragma unroll
    for (int j = 0; j < 4; ++j) {
      int tok = m0 + wr * 64 + i * 16 + lq * 4;
      int col = n0 + wc * 64 + j * 16 + lm;
      float* op = out + (size_t)tok * NFEAT + col;
#pragma unroll
      for (int rg = 0; rg < 4; ++rg) op[(size_t)rg * NFEAT] = acc[i][j][rg];
    }
  }
}

extern "C" void kernel_launch(void* const* d_in, const int* in_sizes, int n_in,
                              void* d_out, int out_size, void* d_ws, size_t ws_size,
                              hipStream_t stream) {
  const float* x = (const float*)d_in[0];        // [16384, 512] f32
  const float* coeffs = (const float*)d_in[1];   // [512, 512, 12] f32
  float* out = (float*)d_out;                    // [16384, 512] f32
  unsigned char* codeT = (unsigned char*)d_ws;                                   // 576*16384 = 9.44 MB
  unsigned short* Bmat = (unsigned short*)((char*)d_ws + (size_t)576 * MTOT);    // 512*4608*2 = 4.72 MB

  build_codes<<<dim3(64, 8), dim3(256), 0, stream>>>(x, codeT);
  build_b<<<dim3(2048), dim3(256), 0, stream>>>(coeffs, Bmat);
  kan_gemm<<<dim3(512), dim3(256), 0, stream>>>(codeT, Bmat, out);
}

// Round 3
// 171.560 us; speedup vs baseline: 1.3731x; 1.2956x over previous
//
#include <hip/hip_runtime.h>

#define MTOT 16384        // 8*2048 tokens
#define NFEAT 512         // out features
#define KTOT 4608         // 512 inputs * 9 segments

typedef float f32x4 __attribute__((ext_vector_type(4)));
typedef short s16x8 __attribute__((ext_vector_type(8)));

__device__ __forceinline__ int div9(int c) { return (c * 7282) >> 16; }  // exact for 0 <= c < 32768

#define GLDS(GP, LP) __builtin_amdgcn_global_load_lds( \
    (const __attribute__((address_space(1))) void*)(GP), \
    (__attribute__((address_space(3))) void*)(LP), 16, 0, 0)

// branchless decode: one code byte -> 8 bf16 one-hot fragment
__device__ __forceinline__ s16x8 decode_frag(unsigned code) {
  unsigned nb0 = code & 15u, nb1 = code >> 4;
  unsigned p0 = nb0 - 1u, p1 = nb1 - 1u;  // wraps to 0xFFFFFFFF when nb==0
  unsigned long long v0 = (nb0 ? 0x3F80ull : 0ull) << ((p0 & 3u) << 4);
  unsigned long long v1 = (nb1 ? 0x3F80ull : 0ull) << ((p1 & 3u) << 4);
  unsigned long long lo = (p0 < 4u ? v0 : 0ull) | (p1 < 4u ? v1 : 0ull);
  unsigned long long hi = (p0 < 4u ? 0ull : v0) | (p1 < 4u ? 0ull : v1);
  union { unsigned long long q[2]; s16x8 v; } u;
  u.q[0] = lo; u.q[1] = hi;
  return u.v;
}

// ---------------- fused prep: bx<2048 -> build_b, else build_codes ----------------
__global__ __launch_bounds__(256) void prep(const float* __restrict__ x,
                                            const float* __restrict__ coeffs,
                                            unsigned char* __restrict__ codeT,
                                            unsigned short* __restrict__ Bmat) {
  __shared__ unsigned char segt[64][68];
  const int bx = blockIdx.x;
  const int tid = threadIdx.x;
  if (bx < 2048) {
    // ---- build_b: coeffs -> Bmat[i][k] bf16, k = j*9+s ----
    const int i = bx >> 2, q = bx & 3;
    const float* cb = coeffs + (size_t)i * 6144;
#pragma unroll
    for (int p = 0; p < 5; ++p) {
      int kl = p * 256 + tid;
      if (kl < 1152) {
        int k = q * 1152 + kl;
        int j = div9(k), s = k - j * 9;
        float v = cb[j * 12 + s] + cb[j * 12 + s + 1] + cb[j * 12 + s + 2];
        unsigned u = __float_as_uint(v);
        unsigned rn = (u + 0x7FFFu + ((u >> 16) & 1u)) >> 16;  // RNE f32->bf16
        Bmat[(size_t)i * KTOT + k] = (unsigned short)rn;
      }
    }
  } else {
    // ---- build_codes: x -> codeT[g][m], 64 tokens x 64 inputs per block ----
    const int bb = bx - 2048;
    const int mt = bb >> 3;   // 0..255
    const int jt = bb & 7;    // 0..7
    const int m0 = mt * 64;
    const float4* x4 = (const float4*)x;
    const float T1 = (float)(1.0/9.0), T2 = (float)(2.0/9.0), T3 = (float)(3.0/9.0),
                T4 = (float)(4.0/9.0), T5 = (float)(5.0/9.0), T6 = (float)(6.0/9.0),
                T7 = (float)(7.0/9.0), T8 = (float)(8.0/9.0);
#pragma unroll
    for (int it = 0; it < 4; ++it) {
      int f = it * 256 + tid;
      int m = f >> 4, jq = f & 15;
      float4 v = x4[(size_t)(m0 + m) * 128 + jt * 16 + jq];
      uchar4 sv;
      { float xv = v.x; sv.x = (unsigned char)((xv>=T1)+(xv>=T2)+(xv>=T3)+(xv>=T4)+(xv>=T5)+(xv>=T6)+(xv>=T7)+(xv>=T8)); }
      { float xv = v.y; sv.y = (unsigned char)((xv>=T1)+(xv>=T2)+(xv>=T3)+(xv>=T4)+(xv>=T5)+(xv>=T6)+(xv>=T7)+(xv>=T8)); }
      { float xv = v.z; sv.z = (unsigned char)((xv>=T1)+(xv>=T2)+(xv>=T3)+(xv>=T4)+(xv>=T5)+(xv>=T6)+(xv>=T7)+(xv>=T8)); }
      { float xv = v.w; sv.w = (unsigned char)((xv>=T1)+(xv>=T2)+(xv>=T3)+(xv>=T4)+(xv>=T5)+(xv>=T6)+(xv>=T7)+(xv>=T8)); }
      *(uchar4*)&segt[m][jq * 4] = sv;
    }
    __syncthreads();
#pragma unroll
    for (int p = 0; p < 5; ++p) {
      int u = p * 256 + tid;
      if (u < 1152) {
        int gl = u >> 4, mq = u & 15;
        int c0 = jt * 576 + gl * 8;
        int j0 = div9(c0), j1 = div9(c0 + 7);
        int j0l = j0 - jt * 64, j1l = j1 - jt * 64;
        uchar4 ob;
        unsigned char* pb = (unsigned char*)&ob;
#pragma unroll
        for (int c = 0; c < 4; ++c) {
          int m = mq * 4 + c;
          int s0 = segt[m][j0l];
          int pos0 = j0 * 9 + s0 - c0;
          unsigned code = (pos0 >= 0 && pos0 < 8) ? (unsigned)(pos0 + 1) : 0u;
          if (j1 != j0) {
            int s1 = segt[m][j1l];
            int pos1 = j1 * 9 + s1 - c0;
            if (pos1 < 8) code |= (unsigned)(pos1 + 1) << 4;
          }
          pb[c] = (unsigned char)code;
        }
        *(uchar4*)(codeT + (size_t)(jt * 72 + gl) * MTOT + m0 + mq * 4) = ob;
      }
    }
  }
}

// ---------------- main: one-hot bf16 MFMA GEMM, 4x1 wave split ----------------
__global__ __launch_bounds__(256, 2) void kan_gemm(const unsigned char* __restrict__ codeT,
                                                   const unsigned short* __restrict__ Bmat,
                                                   float* __restrict__ out) {
  __shared__ __align__(16) short Blds[2][16 * 512];  // 2 x 16KB, fragment-major
  const int tid = threadIdx.x;
  const int lane = tid & 63;
  const int wid = tid >> 6;
  const int lm = lane & 15;
  const int lq = lane >> 4;
  const int bx = blockIdx.x;
  const int rr8 = bx & 7, qq = bx >> 3;
  const int nt = rr8 & 3;
  const int mt = qq * 2 + (rr8 >> 2);
  const int m0 = mt * 128, n0 = nt * 128;
  const int wr = wid;  // wave owns m-rows [wr*32, wr*32+32), all 128 n-cols

  // B staging pointers (per-wave slots pp = wid*4 + {0..3})
  const unsigned short* gB0 = Bmat + (size_t)(n0 + (wid * 2 + 0) * 16 + lm) * KTOT + lq * 8;
  const unsigned short* gB1 = Bmat + (size_t)(n0 + (wid * 2 + 1) * 16 + lm) * KTOT + lq * 8;
  // code pointers: frag f = ms*2+ks; addr = (ks*4+lq)*MTOT + m0 + wr*32 + ms*16 + lm
  const unsigned char* gC0 = codeT + (size_t)lq * MTOT + m0 + wr * 32 + lm;        // ks=0
  const unsigned char* gC1 = codeT + (size_t)(4 + lq) * MTOT + m0 + wr * 32 + lm;  // ks=1

  f32x4 acc[2][8] = {};
  s16x8 afA[4], afB[4];
  unsigned char cr[4];

#define LOAD_CR() do { \
    cr[0] = gC0[0]; cr[1] = gC1[0]; cr[2] = gC0[16]; cr[3] = gC1[16]; \
    gC0 += (size_t)8 * MTOT; gC1 += (size_t)8 * MTOT; } while (0)

#define ISSUE_B(buf) do { \
    short* base = &Blds[buf][0] + wid * 2048; \
    GLDS(gB0,      base);        \
    GLDS(gB0 + 32, base + 512);  \
    GLDS(gB1,      base + 1024); \
    GLDS(gB1 + 32, base + 1536); \
    gB0 += 64; gB1 += 64; } while (0)

#define COMPUTE(AF, buf) do { \
    _Pragma("unroll") \
    for (int ks = 0; ks < 2; ++ks) { \
      s16x8 bf[8]; \
      _Pragma("unroll") \
      for (int ns = 0; ns < 8; ++ns) \
        bf[ns] = *(const s16x8*)&Blds[buf][(ns * 2 + ks) * 512 + lane * 8]; \
      _Pragma("unroll") \
      for (int ms = 0; ms < 2; ++ms) \
        _Pragma("unroll") \
        for (int ns = 0; ns < 8; ++ns) \
          acc[ms][ns] = __builtin_amdgcn_mfma_f32_16x16x32_bf16(AF[ms * 2 + ks], bf[ns], acc[ms][ns], 0, 0, 0); \
    } } while (0)

  // prologue: stage kt=0, decode kt=0 frags, prefetch kt=1 codes
  LOAD_CR();
  ISSUE_B(0);
#pragma unroll
  for (int f = 0; f < 4; ++f) afA[f] = decode_frag(cr[f]);
  LOAD_CR();
  __syncthreads();  // Blds[0] ready

#pragma unroll 1
  for (int kt = 0; kt < 72; kt += 2) {
    // phase A: compute kt; prefetch B(kt+1); decode codes(kt+1)->afB; load codes(kt+2)
    ISSUE_B(1);
#pragma unroll
    for (int f = 0; f < 4; ++f) afB[f] = decode_frag(cr[f]);
    if (kt < 70) LOAD_CR();
    COMPUTE(afA, 0);
    __syncthreads();
    // phase B: compute kt+1; prefetch B(kt+2); decode codes(kt+2)->afA; load codes(kt+3)
    if (kt < 70) {
      ISSUE_B(0);
#pragma unroll
      for (int f = 0; f < 4; ++f) afA[f] = decode_frag(cr[f]);
      LOAD_CR();
    }
    COMPUTE(afB, 1);
    __syncthreads();
  }

  // epilogue: C/D layout col=lane&15, row=quad*4+reg (verified R1/R2)
#pragma unroll
  for (int ms = 0; ms < 2; ++ms) {
#pragma unroll
    for (int ns = 0; ns < 8; ++ns) {
      int tok = m0 + wr * 32 + ms * 16 + lq * 4;
      int col = n0 + ns * 16 + lm;
      float* op = out + (size_t)tok * NFEAT + col;
#pragma unroll
      for (int rg = 0; rg < 4; ++rg) op[(size_t)rg * NFEAT] = acc[ms][ns][rg];
    }
  }
}

extern "C" void kernel_launch(void* const* d_in, const int* in_sizes, int n_in,
                              void* d_out, int out_size, void* d_ws, size_t ws_size,
                              hipStream_t stream) {
  const float* x = (const float*)d_in[0];        // [16384, 512] f32
  const float* coeffs = (const float*)d_in[1];   // [512, 512, 12] f32
  float* out = (float*)d_out;                    // [16384, 512] f32
  unsigned char* codeT = (unsigned char*)d_ws;                                  // 576*16384 = 9.44 MB
  unsigned short* Bmat = (unsigned short*)((char*)d_ws + (size_t)576 * MTOT);   // 512*4608*2 = 4.72 MB

  prep<<<dim3(4096), dim3(256), 0, stream>>>(x, coeffs, codeT, Bmat);
  kan_gemm<<<dim3(512), dim3(256), 0, stream>>>(codeT, Bmat, out);
}